// Round 14
// baseline (921.680 us; speedup 1.0000x reference)
//
#include <hip/hip_runtime.h>
#include <math.h>

// Problem constants (match reference: NO=64, H=83, S=4)
#define NO  64
#define H   83
#define HP2 96    // padded row stride: 4 chunks x 24 floats, 16B-aligned
#define CH  24    // per-lane j-chunk (HP2/4)
#define SP  4     // species count

// ---------------------------------------------------------------------------
// Repack W1 [S][NO][H] -> [S][NO][HP2], b1 [S][H] -> [S][HP2], W2 [S][H][1]
// -> [S][HP2], all zero-padded so per-lane chunks are aligned float4 rows and
// pad lanes contribute exactly 0 to every dot product.
__global__ void repack_params(const float* __restrict__ W1,
                              const float* __restrict__ b1,
                              const float* __restrict__ W2,
                              float* __restrict__ wsf) {
    int idx = blockIdx.x * 256 + threadIdx.x;
    const int w1e = SP * NO * HP2;                 // 24576 floats
    const int tot = w1e + 2 * SP * HP2;            // + b1p + w2p
    if (idx >= tot) return;
    if (idx < w1e) {
        int j  = idx % HP2;
        int sk = idx / HP2;                        // s*NO + k
        wsf[idx] = (j < H) ? W1[sk * H + j] : 0.0f;
    } else if (idx < w1e + SP * HP2) {
        int r = idx - w1e;
        int j = r % HP2, s = r / HP2;
        wsf[idx] = (j < H) ? b1[s * H + j] : 0.0f;
    } else {
        int r = idx - w1e - SP * HP2;
        int j = r % HP2, s = r / HP2;
        wsf[idx] = (j < H) ? W2[s * H + j] : 0.0f;
    }
}

// ---------------------------------------------------------------------------
// j-split fused kernel: 4 lanes per atom, lane g owns z1[g*24 .. g*24+23].
//
// R11/R13 postmortem: the 1-thread-per-atom form needs ~110 live regs; the
// allocator pinned at VGPR=128 with partial spill REGARDLESS of
// __launch_bounds__(256,2) or amdgpu_waves_per_eu(2,2) (both measured: 128
// regs, 470 MB HBM scratch/scatter traffic, VALUBusy 28%, Occ 22%, ~770 us).
// This version makes spill impossible by construction (~60 live regs) and
// runs at default 6-8 waves/EU for latency hiding.
//
// Cross-lane cost is tiny because force is LINEAR in gd: each lane
// accumulates f from its own partial dot; one 8-shuffle butterfly at the end
// merges (es, f0, f1, f2) across the 4-lane group.
//
// No species sort: per-lane W1 bases are vector addresses (<=4 x 64B L1
// segments per row load, below the FMA floor), and dropping the sort makes
// pos reads and all output writes fully coalesced (R13's WRITE was 38x the
// real output bytes from scattered write-allocate across XCD L2s).
__global__ void atoms_split(const int*   __restrict__ sym,
                            const float* __restrict__ pos,
                            const float* __restrict__ Wd,    // [3][NO]
                            const float* __restrict__ wsf,   // packed params
                            const float* __restrict__ b2,    // [S]
                            float* __restrict__ energies,
                            float* __restrict__ forces,
                            int n) {
    int gid  = blockIdx.x * 256 + threadIdx.x;
    int atom = gid >> 2;
    int g    = gid & 3;
    if (atom >= n) return;
    int s = sym[atom];

    float p0 = pos[3 * atom + 0];
    float p1 = pos[3 * atom + 1];
    float p2 = pos[3 * atom + 2];

    const float* w1s = wsf + s * NO * HP2 + g * CH;            // my chunk col
    const float* b1s = wsf + SP * NO * HP2 + s * HP2 + g * CH;
    const float* w2s = wsf + SP * NO * HP2 + SP * HP2 + s * HP2 + g * CH;

    // ---- init z1 chunk from padded b1 ----
    float z1[CH];
    {
        const float4* b4 = reinterpret_cast<const float4*>(b1s);
#pragma unroll
        for (int q = 0; q < CH / 4; ++q) {
            float4 v = b4[q];
            z1[4 * q + 0] = v.x; z1[4 * q + 1] = v.y;
            z1[4 * q + 2] = v.z; z1[4 * q + 3] = v.w;
        }
    }

    // ---- phase 1: z1 += sin(p@Wd_k) * W1[k, my chunk] ----
    for (int k = 0; k < NO; ++k) {
        float z0 = fmaf(p0, Wd[k], fmaf(p1, Wd[NO + k], p2 * Wd[2 * NO + k]));
        float d  = __sinf(z0);
        const float4* row = reinterpret_cast<const float4*>(w1s + k * HP2);
#pragma unroll
        for (int q = 0; q < CH / 4; ++q) {
            float4 w = row[q];
            z1[4 * q + 0] = fmaf(d, w.x, z1[4 * q + 0]);
            z1[4 * q + 1] = fmaf(d, w.y, z1[4 * q + 1]);
            z1[4 * q + 2] = fmaf(d, w.z, z1[4 * q + 2]);
            z1[4 * q + 3] = fmaf(d, w.w, z1[4 * q + 3]);
        }
    }

    // ---- phase 2: partial energy + g1 = W2*silu'(z1) in place ----
    // pad j: w2p = 0 -> es contribution 0 and g1 = 0 (safe in phase 3).
    float es = 0.0f;
    {
        const float4* w4 = reinterpret_cast<const float4*>(w2s);
#pragma unroll
        for (int q = 0; q < CH / 4; ++q) {
            float4 wv = w4[q];
            float wcomp[4] = {wv.x, wv.y, wv.z, wv.w};
#pragma unroll
            for (int t = 0; t < 4; ++t) {
                float z  = z1[4 * q + t];
                float sg = 1.0f / (1.0f + __expf(-z));
                float w2 = wcomp[t];
                es = fmaf(z * sg, w2, es);
                z1[4 * q + t] = w2 * sg * fmaf(z, 1.0f - sg, 1.0f);
            }
        }
    }

    // ---- phase 3: lane-partial gd per k feeds force directly (linear) ----
    float f0 = 0.0f, f1 = 0.0f, f2 = 0.0f;
    for (int k = 0; k < NO; ++k) {
        float z0 = fmaf(p0, Wd[k], fmaf(p1, Wd[NO + k], p2 * Wd[2 * NO + k]));
        float c  = __cosf(z0);
        const float4* row = reinterpret_cast<const float4*>(w1s + k * HP2);
        float a0 = 0.f, a1 = 0.f, a2 = 0.f, a3 = 0.f;
#pragma unroll
        for (int q = 0; q < CH / 4; ++q) {
            float4 w = row[q];
            a0 = fmaf(z1[4 * q + 0], w.x, a0);
            a1 = fmaf(z1[4 * q + 1], w.y, a1);
            a2 = fmaf(z1[4 * q + 2], w.z, a2);
            a3 = fmaf(z1[4 * q + 3], w.w, a3);
        }
        float gdp = (a0 + a1) + (a2 + a3);      // my 24-wide partial of gd_k
        float gc  = gdp * c;
        f0 = fmaf(gc, Wd[k], f0);
        f1 = fmaf(gc, Wd[NO + k], f1);
        f2 = fmaf(gc, Wd[2 * NO + k], f2);
    }

    // ---- merge the 4-lane group (butterfly keeps all lanes valid) ----
    es += __shfl_xor(es, 1); es += __shfl_xor(es, 2);
    f0 += __shfl_xor(f0, 1); f0 += __shfl_xor(f0, 2);
    f1 += __shfl_xor(f1, 1); f1 += __shfl_xor(f1, 2);
    f2 += __shfl_xor(f2, 1); f2 += __shfl_xor(f2, 2);

    if (g == 0) {
        energies[atom]       = es + b2[s];
        forces[3 * atom + 0] = f0;
        forces[3 * atom + 1] = f1;
        forces[3 * atom + 2] = f2;
    }
}

// ---------------------------------------------------------------------------
// Correctness parachute if ws is too small for the 101 KB repack: same
// j-split structure, scalar guarded loads straight from the raw params.
__global__ void atoms_split_fb(const int*   __restrict__ sym,
                               const float* __restrict__ pos,
                               const float* __restrict__ Wd,
                               const float* __restrict__ W1,  // [S][NO][H]
                               const float* __restrict__ b1,  // [S][H]
                               const float* __restrict__ W2,  // [S][H]
                               const float* __restrict__ b2,  // [S]
                               float* __restrict__ energies,
                               float* __restrict__ forces,
                               int n) {
    int gid  = blockIdx.x * 256 + threadIdx.x;
    int atom = gid >> 2;
    int g    = gid & 3;
    if (atom >= n) return;
    int s  = sym[atom];
    int j0 = g * 21;                                  // 4 x 21 covers 83

    float p0 = pos[3 * atom], p1 = pos[3 * atom + 1], p2 = pos[3 * atom + 2];
    const float* w1s = W1 + (size_t)s * NO * H;
    float z1[21];
#pragma unroll
    for (int jj = 0; jj < 21; ++jj)
        z1[jj] = (j0 + jj < H) ? b1[s * H + j0 + jj] : 0.0f;

    for (int k = 0; k < NO; ++k) {
        float z0 = fmaf(p0, Wd[k], fmaf(p1, Wd[NO + k], p2 * Wd[2 * NO + k]));
        float d  = __sinf(z0);
        const float* row = w1s + k * H;
#pragma unroll
        for (int jj = 0; jj < 21; ++jj)
            z1[jj] = fmaf(d, (j0 + jj < H) ? row[j0 + jj] : 0.0f, z1[jj]);
    }
    float es = 0.0f;
#pragma unroll
    for (int jj = 0; jj < 21; ++jj) {
        float z  = z1[jj];
        float sg = 1.0f / (1.0f + __expf(-z));
        float w2 = (j0 + jj < H) ? W2[s * H + j0 + jj] : 0.0f;
        es = fmaf(z * sg, w2, es);
        z1[jj] = w2 * sg * fmaf(z, 1.0f - sg, 1.0f);
    }
    float f0 = 0.f, f1 = 0.f, f2 = 0.f;
    for (int k = 0; k < NO; ++k) {
        float z0 = fmaf(p0, Wd[k], fmaf(p1, Wd[NO + k], p2 * Wd[2 * NO + k]));
        float c  = __cosf(z0);
        const float* row = w1s + k * H;
        float acc = 0.f;
#pragma unroll
        for (int jj = 0; jj < 21; ++jj)
            acc = fmaf(z1[jj], (j0 + jj < H) ? row[j0 + jj] : 0.0f, acc);
        float gc = acc * c;
        f0 = fmaf(gc, Wd[k], f0);
        f1 = fmaf(gc, Wd[NO + k], f1);
        f2 = fmaf(gc, Wd[2 * NO + k], f2);
    }
    es += __shfl_xor(es, 1); es += __shfl_xor(es, 2);
    f0 += __shfl_xor(f0, 1); f0 += __shfl_xor(f0, 2);
    f1 += __shfl_xor(f1, 1); f1 += __shfl_xor(f1, 2);
    f2 += __shfl_xor(f2, 1); f2 += __shfl_xor(f2, 2);
    if (g == 0) {
        energies[atom]       = es + b2[s];
        forces[3 * atom + 0] = f0;
        forces[3 * atom + 1] = f1;
        forces[3 * atom + 2] = f2;
    }
}

// ---------------------------------------------------------------------------
// Per-crystal energy: crystalidx is sorted in original atom order -> binary
// search segment bounds, strided sum, butterfly reduce. No atomics.
__global__ void crystal_energy(const int* __restrict__ cidx,
                               const float* __restrict__ energies,
                               float* __restrict__ energy, int n) {
    int c = blockIdx.x;
    int lane = threadIdx.x;           // 64 threads
    int lo = 0, hi = n;
    while (lo < hi) { int mid = (lo + hi) >> 1; if (cidx[mid] < c) lo = mid + 1; else hi = mid; }
    int start = lo;
    hi = n;
    while (lo < hi) { int mid = (lo + hi) >> 1; if (cidx[mid] < c + 1) lo = mid + 1; else hi = mid; }
    int end = lo;
    float sum = 0.0f;
    for (int i = start + lane; i < end; i += 64) sum += energies[i];
    for (int off = 32; off; off >>= 1) sum += __shfl_down(sum, off);
    if (lane == 0) energy[c] = sum;
}

// ---------------------------------------------------------------------------
extern "C" void kernel_launch(void* const* d_in, const int* in_sizes, int n_in,
                              void* d_out, int out_size, void* d_ws, size_t ws_size,
                              hipStream_t stream) {
    const int*   sym  = (const int*)d_in[0];
    const float* pos  = (const float*)d_in[1];
    // d_in[2] = cells  (unused by the stand-in descriptor)
    const int*   cidx = (const int*)d_in[3];
    // d_in[4] = pbcs   (unused)
    const float* Wd   = (const float*)d_in[5];
    const float* W1   = (const float*)d_in[6];
    const float* b1   = (const float*)d_in[7];
    const float* W2   = (const float*)d_in[8];
    const float* b2   = (const float*)d_in[9];

    int nta = in_sizes[0];
    int nc  = in_sizes[2] / 9;

    float* energies = (float*)d_out;          // [nta]
    float* energy   = energies + nta;         // [nc]
    float* forces   = energy + nc;            // [nta*3]

    // workspace: packed padded params, 25344 floats = 101376 B
    const int pack_elems = SP * NO * HP2 + 2 * SP * HP2;
    size_t need = (size_t)pack_elems * sizeof(float);
    float* wsf = (float*)d_ws;

    int nthreads = 4 * nta;                   // 4 lanes per atom
    int nblk = (nthreads + 255) / 256;

    if (ws_size >= need) {
        repack_params<<<(pack_elems + 255) / 256, 256, 0, stream>>>(W1, b1, W2, wsf);
        atoms_split<<<nblk, 256, 0, stream>>>(
            sym, pos, Wd, wsf, b2, energies, forces, nta);
    } else {
        atoms_split_fb<<<nblk, 256, 0, stream>>>(
            sym, pos, Wd, W1, b1, W2, b2, energies, forces, nta);
    }
    crystal_energy<<<nc, 64, 0, stream>>>(cidx, energies, energy, nta);
}